// Round 7
// baseline (385.912 us; speedup 1.0000x reference)
//
#include <hip/hip_runtime.h>

#define E   128
#define HD  32
#define NB  512
#define NN  65536
#define TT  (NB + NN)   // 66048 tokens: [0,NB) metal, [NB,TT) nodes
#define TE  ((size_t)TT * 128)

typedef __attribute__((ext_vector_type(8))) short short8;
typedef __attribute__((ext_vector_type(4))) float f32x4;

enum { AF32 = 0, ASPLIT = 1 };
enum { OF32T = 0, OSPLITT = 1, OSPLITSEQ = 2, OBF16SEQ = 3 };

__device__ __forceinline__ const float* row_ptr(const float* base, const float* metal, int t) {
  return (t < NB) ? metal + (size_t)t * E : base + (size_t)(t - NB) * E;
}
__device__ __forceinline__ float* row_ptr_w(float* base, float* metal, int t) {
  return (t < NB) ? metal + (size_t)t * E : base + (size_t)(t - NB) * E;
}

__device__ __forceinline__ unsigned short f2bf_rne(float x) {
  unsigned u = __float_as_uint(x);
  return (unsigned short)((u + 0x7FFFu + ((u >> 16) & 1u)) >> 16);
}
__device__ __forceinline__ void split_bf(float x, unsigned short& h, unsigned short& l) {
  h = f2bf_rne(x);
  float hf = __uint_as_float(((unsigned)h) << 16);
  l = f2bf_rne(x - hf);
}

// start[b] = first node index of graph b (batch sorted); start[NB] = NN.
__global__ void k_starts(const int* __restrict__ batch, int* __restrict__ start) {
  int i = blockIdx.x * blockDim.x + threadIdx.x;
  if (i >= NN) return;
  int bi = batch[i];
  int bp = (i == 0) ? -1 : batch[i - 1];
  for (int b = bp + 1; b <= bi; ++b) start[b] = i;
  if (i == NN - 1)
    for (int b = bi + 1; b <= NB; ++b) start[b] = NN;
}

// seq row of token t: metal g -> start[g]+g ; node i -> i + batch[i] + 1
__global__ void k_seqmap(const int* __restrict__ batch, const int* __restrict__ start,
                         int* __restrict__ seqmap) {
  int t = blockIdx.x * 256 + threadIdx.x;
  if (t >= TT) return;
  seqmap[t] = (t < NB) ? (start[t] + t) : (t - NB + batch[t - NB] + 1);
}

// Split weights to hi/lo bf16. Rows: [0,128)Wq | [128,256)Wk | [256,640)in_w | [640,768)out_w
__global__ void k_wconv(const float* __restrict__ Wq, const float* __restrict__ Wk,
                        const float* __restrict__ in_w, const float* __restrict__ out_w,
                        unsigned short* __restrict__ Wh, unsigned short* __restrict__ Wl) {
  int idx = blockIdx.x * 256 + threadIdx.x;
  int r = idx >> 7, c = idx & 127;
  float v;
  if (r < 128)      v = Wq[r * 128 + c];
  else if (r < 256) v = Wk[(r - 128) * 128 + c];
  else if (r < 640) v = in_w[(r - 256) * 128 + c];
  else              v = out_w[(r - 640) * 128 + c];
  unsigned short h, l;
  split_bf(v, h, l);
  Wh[idx] = h;
  Wl[idx] = l;
}

// C = act(A @ W^T + b) [* postscale] via split-bf16 MFMA.
// LDS-FREE: A and W fragments loaded directly from global (W is L2-resident,
// A frag pattern covers contiguous row slices -> L1-coalesced). No barriers;
// latency hidden by ILP (20 independent 16B loads per k-chunk).
template <int AM, int OM, bool RELU>
__global__ __launch_bounds__(256, 2)
void k_gemm(const float* __restrict__ Ax, const float* __restrict__ Am,
            const int* __restrict__ rowmap,
            const unsigned short* __restrict__ Ah, const unsigned short* __restrict__ Al,
            const unsigned short* __restrict__ Wh, const unsigned short* __restrict__ Wl,
            const float* __restrict__ bias, float postscale,
            float* __restrict__ Cx, float* __restrict__ Cm,
            unsigned short* __restrict__ Oh, unsigned short* __restrict__ Ol,
            const int* __restrict__ seqmap) {
  const int tid = threadIdx.x;
  const int wave = tid >> 6;
  const int lane = tid & 63;
  const int lrow = lane & 15;
  const int quad = lane >> 4;
  const int t0 = blockIdx.x * 128;

  // Hoist per-row A pointers for this lane's two M-frags.
  const float* arp[2];
  size_t aoff[2];
  #pragma unroll
  for (int mt = 0; mt < 2; ++mt) {
    int m = t0 + wave * 32 + mt * 16 + lrow;
    if (AM == AF32)
      arp[mt] = rowmap ? Ax + (size_t)rowmap[m] * E : row_ptr(Ax, Am, m);
    else
      aoff[mt] = (size_t)m * 128;
  }

  f32x4 acc[2][8];
  #pragma unroll
  for (int mt = 0; mt < 2; ++mt)
    #pragma unroll
    for (int nt = 0; nt < 8; ++nt) acc[mt][nt] = (f32x4){0.f, 0.f, 0.f, 0.f};

  #pragma unroll
  for (int ks = 0; ks < 4; ++ks) {
    const int k0 = ks * 32 + quad * 8;   // this lane's k-offset within row

    short8 ah[2], al[2];
    #pragma unroll
    for (int mt = 0; mt < 2; ++mt) {
      if (AM == AF32) {
        float4 f0 = *(const float4*)(arp[mt] + k0);
        float4 f1 = *(const float4*)(arp[mt] + k0 + 4);
        unsigned short h, l;
        split_bf(f0.x, h, l); ah[mt][0] = (short)h; al[mt][0] = (short)l;
        split_bf(f0.y, h, l); ah[mt][1] = (short)h; al[mt][1] = (short)l;
        split_bf(f0.z, h, l); ah[mt][2] = (short)h; al[mt][2] = (short)l;
        split_bf(f0.w, h, l); ah[mt][3] = (short)h; al[mt][3] = (short)l;
        split_bf(f1.x, h, l); ah[mt][4] = (short)h; al[mt][4] = (short)l;
        split_bf(f1.y, h, l); ah[mt][5] = (short)h; al[mt][5] = (short)l;
        split_bf(f1.z, h, l); ah[mt][6] = (short)h; al[mt][6] = (short)l;
        split_bf(f1.w, h, l); ah[mt][7] = (short)h; al[mt][7] = (short)l;
      } else {
        ah[mt] = *(const short8*)(Ah + aoff[mt] + k0);
        al[mt] = *(const short8*)(Al + aoff[mt] + k0);
      }
    }

    #pragma unroll
    for (int nt = 0; nt < 8; ++nt) {
      const int j = nt * 16 + lrow;       // output col / W row
      short8 bh = *(const short8*)(Wh + (size_t)j * 128 + k0);
      short8 bl = *(const short8*)(Wl + (size_t)j * 128 + k0);
      #pragma unroll
      for (int mt = 0; mt < 2; ++mt) {
        acc[mt][nt] = __builtin_amdgcn_mfma_f32_16x16x32_bf16(ah[mt], bh, acc[mt][nt], 0, 0, 0);
        acc[mt][nt] = __builtin_amdgcn_mfma_f32_16x16x32_bf16(al[mt], bh, acc[mt][nt], 0, 0, 0);
        acc[mt][nt] = __builtin_amdgcn_mfma_f32_16x16x32_bf16(ah[mt], bl, acc[mt][nt], 0, 0, 0);
      }
    }
  }

  // Epilogue. C/D layout: col = lane&15, row = quad*4 + reg.
  #pragma unroll
  for (int mt = 0; mt < 2; ++mt) {
    #pragma unroll
    for (int reg = 0; reg < 4; ++reg) {
      int t = t0 + wave * 32 + mt * 16 + quad * 4 + reg;
      float* cp = nullptr;
      size_t ro = 0;
      if (OM == OF32T) cp = row_ptr_w(Cx, Cm, t);
      else if (OM == OSPLITT) ro = (size_t)t * 128;
      else ro = (size_t)seqmap[t] * 128;
      #pragma unroll
      for (int nt = 0; nt < 8; ++nt) {
        int j = nt * 16 + lrow;
        float v = acc[mt][nt][reg] + bias[j];
        if (RELU) v = fmaxf(v, 0.f);
        v *= postscale;
        if (OM == OF32T) {
          cp[j] = v;
        } else if (OM == OBF16SEQ) {
          Oh[ro + j] = f2bf_rne(v);
        } else {
          unsigned short h, l;
          split_bf(v, h, l);
          Oh[ro + j] = h;
          Ol[ro + j] = l;
        }
      }
    }
  }
}

// Flash attention: grid (NB, 6), 4 waves = 4 heads, 32 queries/block.
// Q/K pre-split bf16 seq-order global (scale*log2e folded into Q); V bf16 seq-order.
__global__ __launch_bounds__(256, 3)
void k_flash(const unsigned short* __restrict__ Qh, const unsigned short* __restrict__ Ql,
             const unsigned short* __restrict__ Kh, const unsigned short* __restrict__ Kl,
             const unsigned short* __restrict__ Vb, const int* __restrict__ start,
             float* __restrict__ ctx) {
  __shared__ unsigned short Vlds[32][134];       // 8576 B, odd-word row stride (67 words)
  __shared__ unsigned short Pld[4][2][32][40];   // [wave][hi/lo][row][key] 20480 B
  const int g = blockIdx.x;
  const int tid = threadIdx.x;
  const int wv = tid >> 6;        // head
  const int lane = tid & 63;
  const int lrow = lane & 15;
  const int quad = lane >> 4;
  const int s0 = start[g];
  const int c = start[g + 1] - s0 + 1;   // slots incl. metal at 0
  const int sbase = s0 + g;
  const int hoff = wv * 32 + quad * 8;   // k-dim offset for frags

  for (int qb = 32 * blockIdx.y; qb < c; qb += 32 * gridDim.y) {
    short8 qfh[2], qfl[2];
    #pragma unroll
    for (int mt = 0; mt < 2; ++mt) {
      int qs = qb + mt * 16 + lrow; if (qs >= c) qs = 0;
      size_t off = (size_t)(sbase + qs) * 128 + hoff;
      qfh[mt] = *(const short8*)(Qh + off);
      qfl[mt] = *(const short8*)(Ql + off);
    }
    float mr[2][4], lr[2][4];
    f32x4 O[2][2];
    #pragma unroll
    for (int mt = 0; mt < 2; ++mt) {
      #pragma unroll
      for (int r4 = 0; r4 < 4; ++r4) { mr[mt][r4] = -3.0e38f; lr[mt][r4] = 0.f; }
      O[mt][0] = (f32x4){0.f, 0.f, 0.f, 0.f};
      O[mt][1] = (f32x4){0.f, 0.f, 0.f, 0.f};
    }

    const int nch = (c + 31) >> 5;
    for (int ch = 0; ch < nch; ++ch) {
      const int kb = ch * 32;
      short8 kfh[2], kfl[2];
      #pragma unroll
      for (int s = 0; s < 2; ++s) {
        int ks = kb + s * 16 + lrow; if (ks >= c) ks = 0;
        size_t off = (size_t)(sbase + ks) * 128 + hoff;
        kfh[s] = *(const short8*)(Kh + off);
        kfl[s] = *(const short8*)(Kl + off);
      }
      __syncthreads();   // previous chunk's Vlds reads complete
      #pragma unroll
      for (int r = 0; r < 2; ++r) {
        int key = r * 16 + (tid >> 4);
        int seg = tid & 15;
        int ks = kb + key; if (ks >= c) ks = 0;
        uint4 v = *(const uint4*)(Vb + (size_t)(sbase + ks) * 128 + seg * 8);
        unsigned* dst = (unsigned*)&Vlds[key][seg * 8];
        dst[0] = v.x; dst[1] = v.y; dst[2] = v.z; dst[3] = v.w;
      }
      __syncthreads();

      f32x4 sv[2][2];
      #pragma unroll
      for (int mt = 0; mt < 2; ++mt)
        #pragma unroll
        for (int s = 0; s < 2; ++s) {
          f32x4 z = (f32x4){0.f, 0.f, 0.f, 0.f};
          z = __builtin_amdgcn_mfma_f32_16x16x32_bf16(qfh[mt], kfh[s], z, 0, 0, 0);
          z = __builtin_amdgcn_mfma_f32_16x16x32_bf16(qfl[mt], kfh[s], z, 0, 0, 0);
          z = __builtin_amdgcn_mfma_f32_16x16x32_bf16(qfh[mt], kfl[s], z, 0, 0, 0);
          sv[mt][s] = z;
        }
      const bool v0 = (kb + lrow) < c;
      const bool v1 = (kb + 16 + lrow) < c;

      #pragma unroll
      for (int mt = 0; mt < 2; ++mt) {
        float mn[4], al[4], p0[4], p1[4], rs[4];
        #pragma unroll
        for (int r4 = 0; r4 < 4; ++r4) {
          float a = v0 ? sv[mt][0][r4] : -3.0e38f;
          float b = v1 ? sv[mt][1][r4] : -3.0e38f;
          sv[mt][0][r4] = a; sv[mt][1][r4] = b;
          mn[r4] = fmaxf(mr[mt][r4], fmaxf(a, b));
        }
        #pragma unroll
        for (int st = 1; st < 16; st <<= 1)
          #pragma unroll
          for (int r4 = 0; r4 < 4; ++r4)
            mn[r4] = fmaxf(mn[r4], __shfl_xor(mn[r4], st, 16));
        #pragma unroll
        for (int r4 = 0; r4 < 4; ++r4) {
          al[r4] = exp2f(mr[mt][r4] - mn[r4]);
          p0[r4] = exp2f(sv[mt][0][r4] - mn[r4]);
          p1[r4] = exp2f(sv[mt][1][r4] - mn[r4]);
          rs[r4] = p0[r4] + p1[r4];
          mr[mt][r4] = mn[r4];
        }
        #pragma unroll
        for (int st = 1; st < 16; st <<= 1)
          #pragma unroll
          for (int r4 = 0; r4 < 4; ++r4)
            rs[r4] += __shfl_xor(rs[r4], st, 16);
        #pragma unroll
        for (int r4 = 0; r4 < 4; ++r4) {
          lr[mt][r4] = lr[mt][r4] * al[r4] + rs[r4];
          int row = mt * 16 + quad * 4 + r4;
          unsigned short h, l;
          split_bf(p0[r4], h, l);
          Pld[wv][0][row][lrow] = h; Pld[wv][1][row][lrow] = l;
          split_bf(p1[r4], h, l);
          Pld[wv][0][row][lrow + 16] = h; Pld[wv][1][row][lrow + 16] = l;
          O[mt][0][r4] *= al[r4];
          O[mt][1][r4] *= al[r4];
        }
      }

      short8 vf[2];
      #pragma unroll
      for (int nt = 0; nt < 2; ++nt)
        #pragma unroll
        for (int jj = 0; jj < 8; ++jj)
          vf[nt][jj] = (short)Vlds[quad * 8 + jj][wv * 32 + nt * 16 + lrow];

      #pragma unroll
      for (int mt = 0; mt < 2; ++mt) {
        short8 ph = *(const short8*)&Pld[wv][0][mt * 16 + lrow][quad * 8];
        short8 pl = *(const short8*)&Pld[wv][1][mt * 16 + lrow][quad * 8];
        #pragma unroll
        for (int nt = 0; nt < 2; ++nt) {
          O[mt][nt] = __builtin_amdgcn_mfma_f32_16x16x32_bf16(ph, vf[nt], O[mt][nt], 0, 0, 0);
          O[mt][nt] = __builtin_amdgcn_mfma_f32_16x16x32_bf16(pl, vf[nt], O[mt][nt], 0, 0, 0);
        }
      }
    }

    #pragma unroll
    for (int mt = 0; mt < 2; ++mt)
      #pragma unroll
      for (int r4 = 0; r4 < 4; ++r4) {
        int qs = qb + mt * 16 + quad * 4 + r4;
        if (qs < c) {
          float inv = 1.f / lr[mt][r4];
          float* cp = ctx + (size_t)(sbase + qs) * 128 + wv * 32 + lrow;
          cp[0]  = O[mt][0][r4] * inv;
          cp[16] = O[mt][1][r4] * inv;
        }
      }
  }
}

extern "C" void kernel_launch(void* const* d_in, const int* in_sizes, int n_in,
                              void* d_out, int out_size, void* d_ws, size_t ws_size,
                              hipStream_t stream) {
  const float* x       = (const float*)d_in[0];
  const float* metal_x = (const float*)d_in[1];
  const int*   batch   = (const int*)d_in[2];
  const float* Wk      = (const float*)d_in[3];
  const float* bk      = (const float*)d_in[4];
  const float* Wq      = (const float*)d_in[5];
  const float* bq      = (const float*)d_in[6];
  const float* in_w    = (const float*)d_in[7];
  const float* in_b    = (const float*)d_in[8];
  const float* out_w   = (const float*)d_in[9];
  const float* out_b   = (const float*)d_in[10];
  float* out = (float*)d_out;

  // ---- workspace layout (float offsets) ----
  // [0,528) start | [528,66576) seqmap | [66576,164880) Wh+Wl (98304 FLOATS total)
  float* ws = (float*)d_ws;
  int* start  = (int*)d_ws;
  int* seqmap = (int*)(ws + 528);
  unsigned short* Wh = (unsigned short*)(ws + 66576);
  unsigned short* Wl = Wh + 768 * 128;
  const size_t BUF0 = 164880;   // = 66576 + 98304  (after BOTH weight halves)
  unsigned short* Hkh = (unsigned short*)(ws + BUF0);        // Hk pair (TE floats)
  unsigned short* Hkl = Hkh + TE;
  float* ctx = ws + BUF0;                                    // reuses Hk slot after K-GEMM
  unsigned short* Qsh = (unsigned short*)(ws + BUF0 + TE);
  unsigned short* Qsl = Qsh + TE;
  unsigned short* Ksh = (unsigned short*)(ws + BUF0 + 2 * TE);
  unsigned short* Ksl = Ksh + TE;
  unsigned short* Vsb = (unsigned short*)(ws + BUF0 + 3 * TE);   // bf16 only (TE/2 floats)
  // peak ws ~= 119.0 MB (< 135.3 MB known-good)
  unsigned short* Hqh = (unsigned short*)d_out;   // Hq pair staged in d_out (TE floats exact)
  unsigned short* Hql = Hqh + TE;

  k_starts<<<NN / 256, 256, 0, stream>>>(batch, start);
  k_seqmap<<<TT / 256, 256, 0, stream>>>(batch, start, seqmap);
  k_wconv<<<768 * 128 / 256, 256, 0, stream>>>(Wq, Wk, in_w, out_w, Wh, Wl);

  const int gb = TT / 128;  // 516
  const float SCL2 = 0.17677669529663687f * 1.4426950408889634f;  // scale*log2(e)
  // V = x@in_w_v^T + b  -> bf16 seq
  k_gemm<AF32, OBF16SEQ, false><<<gb, 256, 0, stream>>>(
      x, metal_x, nullptr, nullptr, nullptr, Wh + 512 * 128, Wl + 512 * 128,
      in_b + 2 * E, 1.f, nullptr, nullptr, Vsb, nullptr, seqmap);
  // Hq = relu(x@Wq^T + bq) -> split pair (token order, in d_out)
  k_gemm<AF32, OSPLITT, true><<<gb, 256, 0, stream>>>(
      x, metal_x, nullptr, nullptr, nullptr, Wh, Wl,
      bq, 1.f, nullptr, nullptr, Hqh, Hql, nullptr);
  // Hk = relu(x@Wk^T + bk) -> split pair (token order)
  k_gemm<AF32, OSPLITT, true><<<gb, 256, 0, stream>>>(
      x, metal_x, nullptr, nullptr, nullptr, Wh + 128 * 128, Wl + 128 * 128,
      bk, 1.f, nullptr, nullptr, Hkh, Hkl, nullptr);
  // Q = Hq@in_w_q^T + b, scaled by scale*log2e -> split pair, seq order
  k_gemm<ASPLIT, OSPLITSEQ, false><<<gb, 256, 0, stream>>>(
      nullptr, nullptr, nullptr, Hqh, Hql, Wh + 256 * 128, Wl + 256 * 128,
      in_b, SCL2, nullptr, nullptr, Qsh, Qsl, seqmap);
  // K = Hk@in_w_k^T + b -> split pair, seq order
  k_gemm<ASPLIT, OSPLITSEQ, false><<<gb, 256, 0, stream>>>(
      nullptr, nullptr, nullptr, Hkh, Hkl, Wh + 384 * 128, Wl + 384 * 128,
      in_b + 128, 1.f, nullptr, nullptr, Ksh, Ksl, seqmap);

  dim3 agrid(NB, 6);
  k_flash<<<agrid, 256, 0, stream>>>(Qsh, Qsl, Ksh, Ksl, Vsb, start, ctx);

  // out = ctx@out_w^T + b (A gathered via seqmap), token-order output
  k_gemm<AF32, OF32T, false><<<gb, 256, 0, stream>>>(
      ctx, nullptr, seqmap, nullptr, nullptr, Wh + 640 * 128, Wl + 640 * 128,
      out_b, 1.f, out, out + (size_t)NN * E, nullptr, nullptr, nullptr);
}

// Round 8
// 329.817 us; speedup vs baseline: 1.1701x; 1.1701x over previous
//
#include <hip/hip_runtime.h>

#define E   128
#define HD  32
#define NB  512
#define NN  65536
#define TT  (NB + NN)   // 66048 tokens: [0,NB) metal, [NB,TT) nodes
#define TE  ((size_t)TT * 128)
#define WMAT 16384      // shorts per matrix in frag-ready layout: 4*8*64*8

typedef __attribute__((ext_vector_type(8))) short short8;
typedef __attribute__((ext_vector_type(4))) float f32x4;

enum { AF32 = 0, ASPLIT = 1 };
enum { OF32T = 0, OSPLITT = 1, OSPLITSEQ = 2, OBF16SEQ = 3 };

__device__ __forceinline__ const float* row_ptr(const float* base, const float* metal, int t) {
  return (t < NB) ? metal + (size_t)t * E : base + (size_t)(t - NB) * E;
}
__device__ __forceinline__ float* row_ptr_w(float* base, float* metal, int t) {
  return (t < NB) ? metal + (size_t)t * E : base + (size_t)(t - NB) * E;
}

__device__ __forceinline__ unsigned short f2bf_rne(float x) {
  unsigned u = __float_as_uint(x);
  return (unsigned short)((u + 0x7FFFu + ((u >> 16) & 1u)) >> 16);
}
__device__ __forceinline__ void split_bf(float x, unsigned short& h, unsigned short& l) {
  h = f2bf_rne(x);
  float hf = __uint_as_float(((unsigned)h) << 16);
  l = f2bf_rne(x - hf);
}

// start[b] = first node index of graph b (batch sorted); start[NB] = NN.
__global__ void k_starts(const int* __restrict__ batch, int* __restrict__ start) {
  int i = blockIdx.x * blockDim.x + threadIdx.x;
  if (i >= NN) return;
  int bi = batch[i];
  int bp = (i == 0) ? -1 : batch[i - 1];
  for (int b = bp + 1; b <= bi; ++b) start[b] = i;
  if (i == NN - 1)
    for (int b = bi + 1; b <= NB; ++b) start[b] = NN;
}

// seq row of token t: metal g -> start[g]+g ; node i -> i + batch[i] + 1
__global__ void k_seqmap(const int* __restrict__ batch, const int* __restrict__ start,
                         int* __restrict__ seqmap) {
  int t = blockIdx.x * 256 + threadIdx.x;
  if (t >= TT) return;
  seqmap[t] = (t < NB) ? (start[t] + t) : (t - NB + batch[t - NB] + 1);
}

// Split weights to hi/lo bf16 in MFMA-FRAG-READY order:
//   Wf[mat][ks][nt][lane][jj]  (lane = quad*16+lrow; frag element jj)
// so a wave's B-frag load is 64 lanes x 16B CONTIGUOUS (coalesced, L1-broadcast
// across waves). mat: 0=Wq 1=Wk 2=in_q 3=in_k 4=in_v 5=out_w.
__global__ void k_wconv(const float* __restrict__ Wq, const float* __restrict__ Wk,
                        const float* __restrict__ in_w, const float* __restrict__ out_w,
                        unsigned short* __restrict__ Wfh, unsigned short* __restrict__ Wfl) {
  int idx = blockIdx.x * 256 + threadIdx.x;   // < 768*128
  int r = idx >> 7, k = idx & 127;            // r: global W row, k: k-index
  float v;
  if (r < 128)      v = Wq[r * 128 + k];
  else if (r < 256) v = Wk[(r - 128) * 128 + k];
  else if (r < 640) v = in_w[(r - 256) * 128 + k];
  else              v = out_w[(r - 640) * 128 + k];
  unsigned short h, l;
  split_bf(v, h, l);
  int mat = r >> 7, j = r & 127;
  int ks = k >> 5, quad = (k >> 3) & 3, jj = k & 7;
  int nt = j >> 4, lrow = j & 15;
  int lane = quad * 16 + lrow;
  size_t di = (size_t)mat * WMAT + (((ks * 8 + nt) * 64 + lane) * 8 + jj);
  Wfh[di] = h;
  Wfl[di] = l;
}

// C = act(A @ W^T + b) [* postscale] via split-bf16 MFMA.
// Zero LDS, zero barriers. W in frag-ready global layout (coalesced 16B/lane
// loads, identical across waves -> L1 broadcast, L2-hot). A read direct from
// global (read-once). K-loop fully unrolled -> ILP hides latency.
template <int AM, int OM, bool RELU>
__global__ __launch_bounds__(256, 2)
void k_gemm(const float* __restrict__ Ax, const float* __restrict__ Am,
            const int* __restrict__ rowmap,
            const unsigned short* __restrict__ Ah, const unsigned short* __restrict__ Al,
            const unsigned short* __restrict__ Wfh, const unsigned short* __restrict__ Wfl,
            const float* __restrict__ bias, float postscale,
            float* __restrict__ Cx, float* __restrict__ Cm,
            unsigned short* __restrict__ Oh, unsigned short* __restrict__ Ol,
            const int* __restrict__ seqmap) {
  const int tid = threadIdx.x;
  const int wave = tid >> 6;
  const int lane = tid & 63;
  const int lrow = lane & 15;
  const int quad = lane >> 4;
  const int t0 = blockIdx.x * 128;

  const float* arp[2];
  size_t aoff[2];
  #pragma unroll
  for (int mt = 0; mt < 2; ++mt) {
    int m = t0 + wave * 32 + mt * 16 + lrow;
    if (AM == AF32)
      arp[mt] = rowmap ? Ax + (size_t)rowmap[m] * E : row_ptr(Ax, Am, m);
    else
      aoff[mt] = (size_t)m * 128;
  }

  f32x4 acc[2][8];
  #pragma unroll
  for (int mt = 0; mt < 2; ++mt)
    #pragma unroll
    for (int nt = 0; nt < 8; ++nt) acc[mt][nt] = (f32x4){0.f, 0.f, 0.f, 0.f};

  #pragma unroll
  for (int ks = 0; ks < 4; ++ks) {
    const int k0 = ks * 32 + quad * 8;   // lane's k-offset within an A row

    short8 ah[2], al[2];
    #pragma unroll
    for (int mt = 0; mt < 2; ++mt) {
      if (AM == AF32) {
        float4 f0 = *(const float4*)(arp[mt] + k0);
        float4 f1 = *(const float4*)(arp[mt] + k0 + 4);
        unsigned short h, l;
        split_bf(f0.x, h, l); ah[mt][0] = (short)h; al[mt][0] = (short)l;
        split_bf(f0.y, h, l); ah[mt][1] = (short)h; al[mt][1] = (short)l;
        split_bf(f0.z, h, l); ah[mt][2] = (short)h; al[mt][2] = (short)l;
        split_bf(f0.w, h, l); ah[mt][3] = (short)h; al[mt][3] = (short)l;
        split_bf(f1.x, h, l); ah[mt][4] = (short)h; al[mt][4] = (short)l;
        split_bf(f1.y, h, l); ah[mt][5] = (short)h; al[mt][5] = (short)l;
        split_bf(f1.z, h, l); ah[mt][6] = (short)h; al[mt][6] = (short)l;
        split_bf(f1.w, h, l); ah[mt][7] = (short)h; al[mt][7] = (short)l;
      } else {
        ah[mt] = *(const short8*)(Ah + aoff[mt] + k0);
        al[mt] = *(const short8*)(Al + aoff[mt] + k0);
      }
    }

    #pragma unroll
    for (int nt = 0; nt < 8; ++nt) {
      // frag-ready: contiguous per lane, same address set for all waves
      const size_t wb = (size_t)(((ks * 8 + nt) * 64 + lane) * 8);
      short8 bh = *(const short8*)(Wfh + wb);
      short8 bl = *(const short8*)(Wfl + wb);
      #pragma unroll
      for (int mt = 0; mt < 2; ++mt) {
        acc[mt][nt] = __builtin_amdgcn_mfma_f32_16x16x32_bf16(ah[mt], bh, acc[mt][nt], 0, 0, 0);
        acc[mt][nt] = __builtin_amdgcn_mfma_f32_16x16x32_bf16(al[mt], bh, acc[mt][nt], 0, 0, 0);
        acc[mt][nt] = __builtin_amdgcn_mfma_f32_16x16x32_bf16(ah[mt], bl, acc[mt][nt], 0, 0, 0);
      }
    }
  }

  // Epilogue. C/D layout: col = lane&15, row = quad*4 + reg.
  #pragma unroll
  for (int mt = 0; mt < 2; ++mt) {
    #pragma unroll
    for (int reg = 0; reg < 4; ++reg) {
      int t = t0 + wave * 32 + mt * 16 + quad * 4 + reg;
      float* cp = nullptr;
      size_t ro = 0;
      if (OM == OF32T) cp = row_ptr_w(Cx, Cm, t);
      else if (OM == OSPLITT) ro = (size_t)t * 128;
      else ro = (size_t)seqmap[t] * 128;
      #pragma unroll
      for (int nt = 0; nt < 8; ++nt) {
        int j = nt * 16 + lrow;
        float v = acc[mt][nt][reg] + bias[j];
        if (RELU) v = fmaxf(v, 0.f);
        v *= postscale;
        if (OM == OF32T) {
          cp[j] = v;
        } else if (OM == OBF16SEQ) {
          Oh[ro + j] = f2bf_rne(v);
        } else {
          unsigned short h, l;
          split_bf(v, h, l);
          Oh[ro + j] = h;
          Ol[ro + j] = l;
        }
      }
    }
  }
}

// Flash attention: grid (NB, 6), 4 waves = 4 heads, 32 queries/block.
// Q/K pre-split bf16 seq-order global (scale*log2e folded into Q); V bf16 seq-order.
__global__ __launch_bounds__(256, 3)
void k_flash(const unsigned short* __restrict__ Qh, const unsigned short* __restrict__ Ql,
             const unsigned short* __restrict__ Kh, const unsigned short* __restrict__ Kl,
             const unsigned short* __restrict__ Vb, const int* __restrict__ start,
             float* __restrict__ ctx) {
  __shared__ unsigned short Vlds[32][134];       // odd-word row stride
  __shared__ unsigned short Pld[4][2][32][40];
  const int g = blockIdx.x;
  const int tid = threadIdx.x;
  const int wv = tid >> 6;
  const int lane = tid & 63;
  const int lrow = lane & 15;
  const int quad = lane >> 4;
  const int s0 = start[g];
  const int c = start[g + 1] - s0 + 1;
  const int sbase = s0 + g;
  const int hoff = wv * 32 + quad * 8;

  for (int qb = 32 * blockIdx.y; qb < c; qb += 32 * gridDim.y) {
    short8 qfh[2], qfl[2];
    #pragma unroll
    for (int mt = 0; mt < 2; ++mt) {
      int qs = qb + mt * 16 + lrow; if (qs >= c) qs = 0;
      size_t off = (size_t)(sbase + qs) * 128 + hoff;
      qfh[mt] = *(const short8*)(Qh + off);
      qfl[mt] = *(const short8*)(Ql + off);
    }
    float mr[2][4], lr[2][4];
    f32x4 O[2][2];
    #pragma unroll
    for (int mt = 0; mt < 2; ++mt) {
      #pragma unroll
      for (int r4 = 0; r4 < 4; ++r4) { mr[mt][r4] = -3.0e38f; lr[mt][r4] = 0.f; }
      O[mt][0] = (f32x4){0.f, 0.f, 0.f, 0.f};
      O[mt][1] = (f32x4){0.f, 0.f, 0.f, 0.f};
    }

    const int nch = (c + 31) >> 5;
    for (int ch = 0; ch < nch; ++ch) {
      const int kb = ch * 32;
      short8 kfh[2], kfl[2];
      #pragma unroll
      for (int s = 0; s < 2; ++s) {
        int ks = kb + s * 16 + lrow; if (ks >= c) ks = 0;
        size_t off = (size_t)(sbase + ks) * 128 + hoff;
        kfh[s] = *(const short8*)(Kh + off);
        kfl[s] = *(const short8*)(Kl + off);
      }
      __syncthreads();
      #pragma unroll
      for (int r = 0; r < 2; ++r) {
        int key = r * 16 + (tid >> 4);
        int seg = tid & 15;
        int ks = kb + key; if (ks >= c) ks = 0;
        uint4 v = *(const uint4*)(Vb + (size_t)(sbase + ks) * 128 + seg * 8);
        unsigned* dst = (unsigned*)&Vlds[key][seg * 8];
        dst[0] = v.x; dst[1] = v.y; dst[2] = v.z; dst[3] = v.w;
      }
      __syncthreads();

      f32x4 sv[2][2];
      #pragma unroll
      for (int mt = 0; mt < 2; ++mt)
        #pragma unroll
        for (int s = 0; s < 2; ++s) {
          f32x4 z = (f32x4){0.f, 0.f, 0.f, 0.f};
          z = __builtin_amdgcn_mfma_f32_16x16x32_bf16(qfh[mt], kfh[s], z, 0, 0, 0);
          z = __builtin_amdgcn_mfma_f32_16x16x32_bf16(qfl[mt], kfh[s], z, 0, 0, 0);
          z = __builtin_amdgcn_mfma_f32_16x16x32_bf16(qfh[mt], kfl[s], z, 0, 0, 0);
          sv[mt][s] = z;
        }
      const bool v0 = (kb + lrow) < c;
      const bool v1 = (kb + 16 + lrow) < c;

      #pragma unroll
      for (int mt = 0; mt < 2; ++mt) {
        float mn[4], al[4], p0[4], p1[4], rs[4];
        #pragma unroll
        for (int r4 = 0; r4 < 4; ++r4) {
          float a = v0 ? sv[mt][0][r4] : -3.0e38f;
          float b = v1 ? sv[mt][1][r4] : -3.0e38f;
          sv[mt][0][r4] = a; sv[mt][1][r4] = b;
          mn[r4] = fmaxf(mr[mt][r4], fmaxf(a, b));
        }
        #pragma unroll
        for (int st = 1; st < 16; st <<= 1)
          #pragma unroll
          for (int r4 = 0; r4 < 4; ++r4)
            mn[r4] = fmaxf(mn[r4], __shfl_xor(mn[r4], st, 16));
        #pragma unroll
        for (int r4 = 0; r4 < 4; ++r4) {
          al[r4] = exp2f(mr[mt][r4] - mn[r4]);
          p0[r4] = exp2f(sv[mt][0][r4] - mn[r4]);
          p1[r4] = exp2f(sv[mt][1][r4] - mn[r4]);
          rs[r4] = p0[r4] + p1[r4];
          mr[mt][r4] = mn[r4];
        }
        #pragma unroll
        for (int st = 1; st < 16; st <<= 1)
          #pragma unroll
          for (int r4 = 0; r4 < 4; ++r4)
            rs[r4] += __shfl_xor(rs[r4], st, 16);
        #pragma unroll
        for (int r4 = 0; r4 < 4; ++r4) {
          lr[mt][r4] = lr[mt][r4] * al[r4] + rs[r4];
          int row = mt * 16 + quad * 4 + r4;
          unsigned short h, l;
          split_bf(p0[r4], h, l);
          Pld[wv][0][row][lrow] = h; Pld[wv][1][row][lrow] = l;
          split_bf(p1[r4], h, l);
          Pld[wv][0][row][lrow + 16] = h; Pld[wv][1][row][lrow + 16] = l;
          O[mt][0][r4] *= al[r4];
          O[mt][1][r4] *= al[r4];
        }
      }

      short8 vf[2];
      #pragma unroll
      for (int nt = 0; nt < 2; ++nt)
        #pragma unroll
        for (int jj = 0; jj < 8; ++jj)
          vf[nt][jj] = (short)Vlds[quad * 8 + jj][wv * 32 + nt * 16 + lrow];

      #pragma unroll
      for (int mt = 0; mt < 2; ++mt) {
        short8 ph = *(const short8*)&Pld[wv][0][mt * 16 + lrow][quad * 8];
        short8 pl = *(const short8*)&Pld[wv][1][mt * 16 + lrow][quad * 8];
        #pragma unroll
        for (int nt = 0; nt < 2; ++nt) {
          O[mt][nt] = __builtin_amdgcn_mfma_f32_16x16x32_bf16(ph, vf[nt], O[mt][nt], 0, 0, 0);
          O[mt][nt] = __builtin_amdgcn_mfma_f32_16x16x32_bf16(pl, vf[nt], O[mt][nt], 0, 0, 0);
        }
      }
    }

    #pragma unroll
    for (int mt = 0; mt < 2; ++mt)
      #pragma unroll
      for (int r4 = 0; r4 < 4; ++r4) {
        int qs = qb + mt * 16 + quad * 4 + r4;
        if (qs < c) {
          float inv = 1.f / lr[mt][r4];
          float* cp = ctx + (size_t)(sbase + qs) * 128 + wv * 32 + lrow;
          cp[0]  = O[mt][0][r4] * inv;
          cp[16] = O[mt][1][r4] * inv;
        }
      }
  }
}

extern "C" void kernel_launch(void* const* d_in, const int* in_sizes, int n_in,
                              void* d_out, int out_size, void* d_ws, size_t ws_size,
                              hipStream_t stream) {
  const float* x       = (const float*)d_in[0];
  const float* metal_x = (const float*)d_in[1];
  const int*   batch   = (const int*)d_in[2];
  const float* Wk      = (const float*)d_in[3];
  const float* bk      = (const float*)d_in[4];
  const float* Wq      = (const float*)d_in[5];
  const float* bq      = (const float*)d_in[6];
  const float* in_w    = (const float*)d_in[7];
  const float* in_b    = (const float*)d_in[8];
  const float* out_w   = (const float*)d_in[9];
  const float* out_b   = (const float*)d_in[10];
  float* out = (float*)d_out;

  // ---- workspace layout (float offsets) ----
  // [0,528) start | [528,66576) seqmap | [66576,164880) Wfh+Wfl (98304 FLOATS total)
  float* ws = (float*)d_ws;
  int* start  = (int*)d_ws;
  int* seqmap = (int*)(ws + 528);
  unsigned short* Wfh = (unsigned short*)(ws + 66576);   // 6*WMAT shorts
  unsigned short* Wfl = Wfh + 6 * WMAT;
  const size_t BUF0 = 164880;   // after BOTH weight halves
  unsigned short* Hkh = (unsigned short*)(ws + BUF0);    // Hk pair (TE floats)
  unsigned short* Hkl = Hkh + TE;
  float* ctx = ws + BUF0;                                // reuses Hk slot after K-GEMM
  unsigned short* Qsh = (unsigned short*)(ws + BUF0 + TE);
  unsigned short* Qsl = Qsh + TE;
  unsigned short* Ksh = (unsigned short*)(ws + BUF0 + 2 * TE);
  unsigned short* Ksl = Ksh + TE;
  unsigned short* Vsb = (unsigned short*)(ws + BUF0 + 3 * TE);   // bf16 only
  // peak ws ~= 119.0 MB (< 135.3 MB known-good)
  unsigned short* Hqh = (unsigned short*)d_out;   // Hq pair in d_out (TE floats exact)
  unsigned short* Hql = Hqh + TE;

  k_starts<<<NN / 256, 256, 0, stream>>>(batch, start);
  k_seqmap<<<TT / 256, 256, 0, stream>>>(batch, start, seqmap);
  k_wconv<<<768 * 128 / 256, 256, 0, stream>>>(Wq, Wk, in_w, out_w, Wfh, Wfl);

  const int gb = TT / 128;  // 516
  const float SCL2 = 0.17677669529663687f * 1.4426950408889634f;  // scale*log2(e)
  // mats: 0=Wq 1=Wk 2=in_q 3=in_k 4=in_v 5=out_w
  // V = x@in_w_v^T + b  -> bf16 seq
  k_gemm<AF32, OBF16SEQ, false><<<gb, 256, 0, stream>>>(
      x, metal_x, nullptr, nullptr, nullptr, Wfh + 4 * WMAT, Wfl + 4 * WMAT,
      in_b + 2 * E, 1.f, nullptr, nullptr, Vsb, nullptr, seqmap);
  // Hq = relu(x@Wq^T + bq) -> split pair (token order, in d_out)
  k_gemm<AF32, OSPLITT, true><<<gb, 256, 0, stream>>>(
      x, metal_x, nullptr, nullptr, nullptr, Wfh, Wfl,
      bq, 1.f, nullptr, nullptr, Hqh, Hql, nullptr);
  // Hk = relu(x@Wk^T + bk) -> split pair (token order)
  k_gemm<AF32, OSPLITT, true><<<gb, 256, 0, stream>>>(
      x, metal_x, nullptr, nullptr, nullptr, Wfh + 1 * WMAT, Wfl + 1 * WMAT,
      bk, 1.f, nullptr, nullptr, Hkh, Hkl, nullptr);
  // Q = Hq@in_w_q^T + b, scaled by scale*log2e -> split pair, seq order
  k_gemm<ASPLIT, OSPLITSEQ, false><<<gb, 256, 0, stream>>>(
      nullptr, nullptr, nullptr, Hqh, Hql, Wfh + 2 * WMAT, Wfl + 2 * WMAT,
      in_b, SCL2, nullptr, nullptr, Qsh, Qsl, seqmap);
  // K = Hk@in_w_k^T + b -> split pair, seq order
  k_gemm<ASPLIT, OSPLITSEQ, false><<<gb, 256, 0, stream>>>(
      nullptr, nullptr, nullptr, Hkh, Hkl, Wfh + 3 * WMAT, Wfl + 3 * WMAT,
      in_b + 128, 1.f, nullptr, nullptr, Ksh, Ksl, seqmap);

  dim3 agrid(NB, 6);
  k_flash<<<agrid, 256, 0, stream>>>(Qsh, Qsl, Ksh, Ksl, Vsb, start, ctx);

  // out = ctx@out_w^T + b (A gathered via seqmap), token-order output
  k_gemm<AF32, OF32T, false><<<gb, 256, 0, stream>>>(
      ctx, nullptr, seqmap, nullptr, nullptr, Wfh + 5 * WMAT, Wfl + 5 * WMAT,
      out_b, 1.f, out, out + (size_t)NN * E, nullptr, nullptr, nullptr);
}